// Round 4
// baseline (58364.685 us; speedup 1.0000x reference)
//
#include <hip/hip_runtime.h>
#include <hip/hip_bf16.h>
#include <math.h>

using bf16 = __hip_bfloat16;

#define B_ 8
#define H_ 384
#define W_ 512
#define HW_ (H_*W_)
#define H2_ 192
#define W2_ 256
#define HW2_ (H2_*W2_)
#define H4_ 96
#define W4_ 128
#define HW4_ (H4_*W4_)

#define TEMP_F 30.0f
#define HARD_Z_F 0.001f
#define EPS_F 1e-6f

// d_out element offsets (float32), in return order
#define O_IT 0
#define O_IW 4718592
#define O_V  9437184
#define O_O  11010048
#define O_GG 12582912
#define O_DG 15728640
#define O_ZT 18874368

// ---- workspace layout: 3 lifetime-multiplexed slots, ceiling 251,662,336 B < 256 MiB ----
// header [0,4096): kinv f32 (288 B at 0), zmax (32 B at 1024)
#define WS_KINV 0
#define WS_ZMAX 1024
// SLOT A [4096, 100667392): splat (zbuf f32 6291456 + acc f32 25165824)
//                           -> flow h2 (100663296) -> e1(50331648)+e2(25165824) -> d0 (100663296)
#define WS_ZBUF 4096
#define WS_ACC  6295552
#define WS_H2   4096
#define WS_E1   4096
#define WS_E2   50335744
#define WS_D0   4096
// SLOT B [100667392, 201330688): flow h1 -> e0 (alive through d0-conv)
#define WS_H1   100667392
#define WS_E0   100667392
// SLOT C [201330688, 251662336): xin (flow then unet) -> d1
#define WS_XIN  201330688
#define WS_D1   201330688

// 3x3 inverse via partial-pivot LU (getrf) + per-column solve (getri semantics),
// all in f32 — matches np.linalg.inv/XLA exactly for this (triangular) K.
__global__ void k_mats(const float* __restrict__ Ks, float* __restrict__ kinv){
#pragma clang fp contract(off)
  int b = threadIdx.x;
  if (b >= B_) return;
  float A[3][3]; int piv[3] = {0,1,2};
  for (int i=0;i<3;i++) for (int j=0;j<3;j++) A[i][j] = Ks[b*9 + i*3 + j];
  for (int k=0;k<3;k++){
    int p = k; float mx = fabsf(A[k][k]);
    for (int i=k+1;i<3;i++){ float v = fabsf(A[i][k]); if (v > mx){ mx = v; p = i; } }
    if (p != k){
      for (int j=0;j<3;j++){ float t = A[k][j]; A[k][j] = A[p][j]; A[p][j] = t; }
      int t = piv[k]; piv[k] = piv[p]; piv[p] = t;
    }
    for (int i=k+1;i<3;i++){
      A[i][k] = A[i][k] / A[k][k];
      for (int j=k+1;j<3;j++) A[i][j] = A[i][j] - A[i][k]*A[k][j];
    }
  }
  for (int col=0; col<3; col++){
    float y0 = (piv[0]==col) ? 1.0f : 0.0f;
    float y1 = (piv[1]==col) ? 1.0f : 0.0f;
    float y2 = (piv[2]==col) ? 1.0f : 0.0f;
    y1 = y1 - A[1][0]*y0;
    y2 = (y2 - A[2][0]*y0) - A[2][1]*y1;
    float x2 = y2 / A[2][2];
    float x1 = (y1 - A[1][2]*x2) / A[1][1];
    float x0 = ((y0 - A[0][1]*x1) - A[0][2]*x2) / A[0][0];
    kinv[b*9 + 0*3 + col] = x0;
    kinv[b*9 + 1*3 + col] = x1;
    kinv[b*9 + 2*3 + col] = x2;
  }
}

// f32 projection, np einsum op order: ((k0*x + k1*y) + k2), contract off (no FMA).
__device__ __forceinline__ void proj_f(const float* __restrict__ Ki,
                                       const float* __restrict__ T,   // dT + b*16
                                       const float* __restrict__ Q,   // Kt + b*9
                                       float d, float px, float py,
                                       float& xt, float& yt, float& z){
#pragma clang fp contract(off)
  float c0 = ((Ki[0]*px + Ki[1]*py) + Ki[2]) * d;
  float c1 = ((Ki[3]*px + Ki[4]*py) + Ki[5]) * d;
  float c2 = ((Ki[6]*px + Ki[7]*py) + Ki[8]) * d;
  float X0 = ((T[0]*c0 + T[1]*c1) + T[2]*c2) + T[3];
  float X1 = ((T[4]*c0 + T[5]*c1) + T[6]*c2) + T[7];
  float X2 = ((T[8]*c0 + T[9]*c1) + T[10]*c2) + T[11];
  float p0 = (Q[0]*X0 + Q[1]*X1) + Q[2]*X2;
  float p1 = (Q[3]*X0 + Q[4]*X1) + Q[5]*X2;
  float p2 = (Q[6]*X0 + Q[7]*X1) + Q[8]*X2;
  z = p2;
  float zc = fmaxf(z, EPS_F);
  xt = p0/zc; yt = p1/zc;
}

__global__ void k_project(const float* __restrict__ Ds, const float* __restrict__ Kt,
                          const float* __restrict__ dT, const float* __restrict__ kinv,
                          unsigned* __restrict__ zmax, float* __restrict__ out){
#pragma clang fp contract(off)
  int pix = blockIdx.x*256 + threadIdx.x;
  int b = blockIdx.y;
  int y = pix / W_, x = pix % W_;
  float d = fmaxf(Ds[b*HW_ + pix], 0.001f);
  float xt, yt, z;
  proj_f(kinv + b*9, dT + b*16, Kt + b*9, d, (float)x, (float)y, xt, yt, z);
  int gi = b*HW_ + pix;
  out[O_GG + 2*gi + 0] = (2.0f*xt + 1.0f)/(float)W_ - 1.0f;
  out[O_GG + 2*gi + 1] = (2.0f*yt + 1.0f)/(float)H_ - 1.0f;
  out[O_ZT + gi] = z;
  float zi = (z > EPS_F) ? z : 0.0f;
  #pragma unroll
  for (int off=32; off; off>>=1) zi = fmaxf(zi, __shfl_down(zi, off, 64));
  __shared__ float sm[4];
  int lane = threadIdx.x & 63, wid = threadIdx.x >> 6;
  if (lane==0) sm[wid]=zi;
  __syncthreads();
  if (threadIdx.x==0){
    float m = fmaxf(fmaxf(sm[0],sm[1]), fmaxf(sm[2],sm[3]));
    atomicMax(zmax + b, __float_as_uint(m));
  }
}

__global__ void k_zbuf(const float* __restrict__ Ds, const float* __restrict__ Kt,
                       const float* __restrict__ dT, const float* __restrict__ kinv,
                       unsigned* __restrict__ zbuf){
#pragma clang fp contract(off)
  int pix = blockIdx.x*256 + threadIdx.x;
  int b = blockIdx.y;
  int y = pix / W_, x = pix % W_;
  float d = fmaxf(Ds[b*HW_ + pix], 0.001f);
  float xv, yv, z;
  proj_f(kinv + b*9, dT + b*16, Kt + b*9, d, (float)x, (float)y, xv, yv, z);
  if (!(z > EPS_F)) return;
  float x0 = floorf(xv), y0 = floorf(yv);
  unsigned zu = __float_as_uint(z);
  #pragma unroll
  for (int c=0;c<4;c++){
    float cx = x0 + (float)(c&1), cy = y0 + (float)(c>>1);
    float bw = (1.0f - fabsf(xv-cx)) * (1.0f - fabsf(yv-cy));
    if (cx>=0.f && cx<(float)W_ && cy>=0.f && cy<(float)H_ && bw>0.f){
      int flat = b*HW_ + (int)cy*W_ + (int)cx;
      atomicMin(zbuf + flat, zu);
    }
  }
}

__global__ void k_acc(const float* __restrict__ Is, const float* __restrict__ Ds,
                      const float* __restrict__ Kt, const float* __restrict__ dT,
                      const float* __restrict__ kinv,
                      const float* __restrict__ zbuf,
                      const unsigned* __restrict__ zmax,
                      float* __restrict__ acc){
#pragma clang fp contract(off)
  int pix = blockIdx.x*256+threadIdx.x;
  int b = blockIdx.y;
  int y = pix / W_, x = pix % W_;
  float d = fmaxf(Ds[b*HW_ + pix], 0.001f);
  float xv, yv, z;
  proj_f(kinv + b*9, dT + b*16, Kt + b*9, d, (float)x, (float)y, xv, yv, z);
  if (!(z > EPS_F)) return;
  float zm = __uint_as_float(zmax[b]) + EPS_F;
  float q = z / zm;
  float w = expf((-TEMP_F) * q);
  float r = Is[(b*3+0)*HW_+pix], g = Is[(b*3+1)*HW_+pix], bl = Is[(b*3+2)*HW_+pix];
  float x0 = floorf(xv), y0 = floorf(yv);
  #pragma unroll
  for (int c=0;c<4;c++){
    float cx = x0 + (float)(c&1), cy = y0 + (float)(c>>1);
    float bw = (1.0f - fabsf(xv-cx)) * (1.0f - fabsf(yv-cy));
    if (cx>=0.f && cx<(float)W_ && cy>=0.f && cy<(float)H_ && bw>0.f){
      int flat = b*HW_ + (int)cy*W_ + (int)cx;
      if (z <= zbuf[flat] + HARD_Z_F){
        float wt = bw*w;
        atomicAdd(acc + flat*4 + 0, wt*r);
        atomicAdd(acc + flat*4 + 1, wt*g);
        atomicAdd(acc + flat*4 + 2, wt*bl);
        atomicAdd(acc + flat*4 + 3, wt);
      }
    }
  }
}

__global__ void k_norm(const float* __restrict__ acc, float* __restrict__ out){
#pragma clang fp contract(off)
  int pix = blockIdx.x*256+threadIdx.x;
  int b = blockIdx.y;
  int gi = b*HW_+pix;
  float4 a = reinterpret_cast<const float4*>(acc)[gi];
  float den = a.w;
  float denc = fmaxf(den, EPS_F);
  bool on = den > EPS_F;
  out[O_IW + (b*3+0)*HW_+pix] = on ? a.x/denc : 0.0f;
  out[O_IW + (b*3+1)*HW_+pix] = on ? a.y/denc : 0.0f;
  out[O_IW + (b*3+2)*HW_+pix] = on ? a.z/denc : 0.0f;
  out[O_V + gi] = fminf(fmaxf(den, 0.0f), 1.0f);
}

__global__ void k_pack_flow(const float* __restrict__ Is, const float* __restrict__ Ds,
                            const float* __restrict__ out, bf16* __restrict__ xin){
  int pix = blockIdx.x*256+threadIdx.x;
  int b = blockIdx.y;
  int gi = b*HW_+pix;
  xin[(b*5+0)*HW_+pix] = __float2bfloat16(Is[(b*3+0)*HW_+pix]);
  xin[(b*5+1)*HW_+pix] = __float2bfloat16(Is[(b*3+1)*HW_+pix]);
  xin[(b*5+2)*HW_+pix] = __float2bfloat16(Is[(b*3+2)*HW_+pix]);
  xin[(b*5+3)*HW_+pix] = __float2bfloat16(Ds[gi]);
  xin[(b*5+4)*HW_+pix] = __float2bfloat16(out[O_V + gi]);
}

__global__ void k_pack_unet(const float* __restrict__ out, bf16* __restrict__ xin){
  int pix = blockIdx.x*256+threadIdx.x;
  int b = blockIdx.y;
  int gi = b*HW_+pix;
  xin[(b*5+0)*HW_+pix] = __float2bfloat16(out[O_IW + (b*3+0)*HW_+pix]);
  xin[(b*5+1)*HW_+pix] = __float2bfloat16(out[O_IW + (b*3+1)*HW_+pix]);
  xin[(b*5+2)*HW_+pix] = __float2bfloat16(out[O_IW + (b*3+2)*HW_+pix]);
  xin[(b*5+3)*HW_+pix] = __float2bfloat16(out[O_V + gi]);
  xin[(b*5+4)*HW_+pix] = __float2bfloat16(out[O_O + gi]);
}

// direct 3x3 conv, SAME padding. stride1: iy=y+ky-1; stride2: iy=2y+ky (jax SAME pad_lo=0)
template<int CIN, int STRIDE, bool RELU>
__global__ void k_conv(const bf16* __restrict__ in, const float* __restrict__ w,
                       const float* __restrict__ bias, bf16* __restrict__ out,
                       int Cout, int Hin, int Win, int Hout, int Wout){
  int xo = blockIdx.x*64 + (threadIdx.x & 63);
  int yo = blockIdx.y*4 + (threadIdx.x >> 6);
  int bc = blockIdx.z;
  int b = bc / Cout, co = bc % Cout;
  if (xo >= Wout || yo >= Hout) return;
  float acc = bias[co];
  const float* wp = w + co*CIN*9;
  const bf16* ip = in + (b*CIN)*Hin*Win;
  for (int ci=0; ci<CIN; ci++){
    const bf16* ch = ip + ci*Hin*Win;
    if (STRIDE==1){
      #pragma unroll
      for (int ky=0; ky<3; ky++){
        int iy = yo + ky - 1;
        if ((unsigned)iy < (unsigned)Hin){
          const bf16* row = ch + iy*Win;
          #pragma unroll
          for (int kx=0; kx<3; kx++){
            int ix = xo + kx - 1;
            if ((unsigned)ix < (unsigned)Win)
              acc += __bfloat162float(row[ix]) * wp[ky*3+kx];
          }
        }
      }
    } else {
      #pragma unroll
      for (int ky=0; ky<3; ky++){
        int iy = 2*yo + ky;
        if (iy < Hin){
          const bf16* row = ch + iy*Win;
          #pragma unroll
          for (int kx=0; kx<3; kx++){
            int ix = 2*xo + kx;
            if (ix < Win)
              acc += __bfloat162float(row[ix]) * wp[ky*3+kx];
          }
        }
      }
    }
    wp += 9;
  }
  if (RELU) acc = fmaxf(acc, 0.0f);
  out[((b*Cout + co)*Hout + yo)*Wout + xo] = __float2bfloat16(acc);
}

// conv over concat([up2(A), B], ch). A at (Hout/2, Wout/2), B at (Hout, Wout).
template<int CA, int CB, bool RELU>
__global__ void k_conv_cat(const bf16* __restrict__ A, const bf16* __restrict__ Bin,
                           const float* __restrict__ w, const float* __restrict__ bias,
                           bf16* __restrict__ out, int Cout, int Hout, int Wout){
  int xo = blockIdx.x*64 + (threadIdx.x & 63);
  int yo = blockIdx.y*4 + (threadIdx.x >> 6);
  int bc = blockIdx.z;
  int b = bc / Cout, co = bc % Cout;
  if (xo >= Wout || yo >= Hout) return;
  int Ha = Hout>>1, Wa = Wout>>1;
  float acc = bias[co];
  const float* wp = w + co*(CA+CB)*9;
  const bf16* ap = A + (b*CA)*Ha*Wa;
  for (int ci=0; ci<CA; ci++){
    const bf16* ch = ap + ci*Ha*Wa;
    #pragma unroll
    for (int ky=0; ky<3; ky++){
      int iy = yo + ky - 1;
      if ((unsigned)iy < (unsigned)Hout){
        const bf16* row = ch + (iy>>1)*Wa;
        #pragma unroll
        for (int kx=0; kx<3; kx++){
          int ix = xo + kx - 1;
          if ((unsigned)ix < (unsigned)Wout)
            acc += __bfloat162float(row[ix>>1]) * wp[ky*3+kx];
        }
      }
    }
    wp += 9;
  }
  const bf16* bp = Bin + (b*CB)*Hout*Wout;
  for (int ci=0; ci<CB; ci++){
    const bf16* ch = bp + ci*Hout*Wout;
    #pragma unroll
    for (int ky=0; ky<3; ky++){
      int iy = yo + ky - 1;
      if ((unsigned)iy < (unsigned)Hout){
        const bf16* row = ch + iy*Wout;
        #pragma unroll
        for (int kx=0; kx<3; kx++){
          int ix = xo + kx - 1;
          if ((unsigned)ix < (unsigned)Wout)
            acc += __bfloat162float(row[ix]) * wp[ky*3+kx];
        }
      }
    }
    wp += 9;
  }
  if (RELU) acc = fmaxf(acc, 0.0f);
  out[((b*Cout + co)*Hout + yo)*Wout + xo] = __float2bfloat16(acc);
}

// final 3-channel 3x3 conv from a 32ch bf16 buffer.
// MODE 0: flow head -> dgrid = tanh(c0,c1), O = sigmoid(c2)
// MODE 1: unet head -> It (fp32, no act)
template<int MODE>
__global__ void k_out3(const bf16* __restrict__ in, const float* __restrict__ w,
                       const float* __restrict__ bias, float* __restrict__ out){
  int pix = blockIdx.x*256+threadIdx.x;
  int b = blockIdx.y;
  int y = pix / W_, x = pix % W_;
  float a0=bias[0], a1=bias[1], a2=bias[2];
  const bf16* ip = in + (b*32)*HW_;
  for (int ci=0; ci<32; ci++){
    const bf16* ch = ip + ci*HW_;
    #pragma unroll
    for (int ky=0; ky<3; ky++){
      int iy = y + ky - 1;
      if ((unsigned)iy < (unsigned)H_){
        const bf16* row = ch + iy*W_;
        #pragma unroll
        for (int kx=0; kx<3; kx++){
          int ix = x + kx - 1;
          if ((unsigned)ix < (unsigned)W_){
            float v = __bfloat162float(row[ix]);
            int kk = ky*3+kx;
            a0 += v * w[(0*32+ci)*9 + kk];
            a1 += v * w[(1*32+ci)*9 + kk];
            a2 += v * w[(2*32+ci)*9 + kk];
          }
        }
      }
    }
  }
  int gi = b*HW_+pix;
  if (MODE==0){
    out[O_DG + (b*2+0)*HW_+pix] = tanhf(a0);
    out[O_DG + (b*2+1)*HW_+pix] = tanhf(a1);
    out[O_O + gi] = 1.0f/(1.0f+expf(-a2));
  } else {
    out[O_IT + (b*3+0)*HW_+pix] = a0;
    out[O_IT + (b*3+1)*HW_+pix] = a1;
    out[O_IT + (b*3+2)*HW_+pix] = a2;
  }
}

extern "C" void kernel_launch(void* const* d_in, const int* in_sizes, int n_in,
                              void* d_out, int out_size, void* d_ws, size_t ws_size,
                              hipStream_t stream){
  const float* Is = (const float*)d_in[0];
  const float* Ds = (const float*)d_in[1];
  const float* Ks = (const float*)d_in[2];
  const float* Kt = (const float*)d_in[3];
  const float* dT = (const float*)d_in[4];
  const float* fw1=(const float*)d_in[5];  const float* fb1=(const float*)d_in[6];
  const float* fw2=(const float*)d_in[7];  const float* fb2=(const float*)d_in[8];
  const float* fw3=(const float*)d_in[9];  const float* fb3=(const float*)d_in[10];
  const float* we0=(const float*)d_in[11]; const float* be0=(const float*)d_in[12];
  const float* we1=(const float*)d_in[13]; const float* be1=(const float*)d_in[14];
  const float* we2=(const float*)d_in[15]; const float* be2=(const float*)d_in[16];
  const float* wd1=(const float*)d_in[17]; const float* bd1=(const float*)d_in[18];
  const float* wd0=(const float*)d_in[19]; const float* bd0=(const float*)d_in[20];
  const float* wo =(const float*)d_in[21]; const float* bo =(const float*)d_in[22];
  float* out = (float*)d_out;
  char* ws = (char*)d_ws;
  float* kinv = (float*)(ws + WS_KINV);
  unsigned* zmax = (unsigned*)(ws + WS_ZMAX);
  unsigned* zbuf = (unsigned*)(ws + WS_ZBUF);
  float* acc = (float*)(ws + WS_ACC);
  bf16* xin = (bf16*)(ws + WS_XIN);
  bf16* h1  = (bf16*)(ws + WS_H1);
  bf16* h2  = (bf16*)(ws + WS_H2);
  bf16* e0  = (bf16*)(ws + WS_E0);
  bf16* e1  = (bf16*)(ws + WS_E1);
  bf16* e2  = (bf16*)(ws + WS_E2);
  bf16* d1  = (bf16*)(ws + WS_D1);
  bf16* d0  = (bf16*)(ws + WS_D0);

  hipMemsetAsync(zmax, 0, 32, stream);
  hipMemsetAsync(zbuf, 0x7f, (size_t)B_*HW_*4, stream);   // ~3.39e38 sentinel (acts as +inf)
  hipMemsetAsync(acc, 0, (size_t)B_*HW_*4*4, stream);

  k_mats<<<1, 64, 0, stream>>>(Ks, kinv);
  dim3 gpix(HW_/256, B_);
  k_project<<<gpix, 256, 0, stream>>>(Ds, Kt, dT, kinv, zmax, out);
  k_zbuf<<<gpix, 256, 0, stream>>>(Ds, Kt, dT, kinv, zbuf);
  k_acc<<<gpix, 256, 0, stream>>>(Is, Ds, Kt, dT, kinv, (const float*)zbuf, zmax, acc);
  k_norm<<<gpix, 256, 0, stream>>>(acc, out);

  // ---- flow net: xin(C), h1(B), h2(A) ----
  k_pack_flow<<<gpix, 256, 0, stream>>>(Is, Ds, out, xin);
  dim3 cb(256);
  dim3 g1(W_/64, H_/4, B_*32);
  k_conv<5,1,true><<<g1, cb, 0, stream>>>(xin, fw1, fb1, h1, 32, H_, W_, H_, W_);
  k_conv<32,1,true><<<g1, cb, 0, stream>>>(h1, fw2, fb2, h2, 32, H_, W_, H_, W_);
  k_out3<0><<<gpix, 256, 0, stream>>>(h2, fw3, fb3, out);

  // ---- unet: xin(C), e0(B), e1+e2(A), d1(C), d0(A) ----
  k_pack_unet<<<gpix, 256, 0, stream>>>(out, xin);
  k_conv<5,1,true><<<g1, cb, 0, stream>>>(xin, we0, be0, e0, 32, H_, W_, H_, W_);
  dim3 g2(W2_/64, H2_/4, B_*64);
  k_conv<32,2,true><<<g2, cb, 0, stream>>>(e0, we1, be1, e1, 64, H_, W_, H2_, W2_);
  dim3 g3(W4_/64, H4_/4, B_*128);
  k_conv<64,2,true><<<g3, cb, 0, stream>>>(e1, we2, be2, e2, 128, H2_, W2_, H4_, W4_);
  dim3 g4(W2_/64, H2_/4, B_*64);
  k_conv_cat<128,64,true><<<g4, cb, 0, stream>>>(e2, e1, wd1, bd1, d1, 64, H2_, W2_);
  dim3 g5(W_/64, H_/4, B_*32);
  k_conv_cat<64,32,true><<<g5, cb, 0, stream>>>(d1, e0, wd0, bd0, d0, 32, H_, W_);
  k_out3<1><<<gpix, 256, 0, stream>>>(d0, wo, bo, out);
}

// Round 5
// 1962.556 us; speedup vs baseline: 29.7391x; 29.7391x over previous
//
#include <hip/hip_runtime.h>
#include <hip/hip_bf16.h>
#include <math.h>

using bf16 = __hip_bfloat16;
using bf16x8 = __attribute__((ext_vector_type(8))) short;
using f32x4  = __attribute__((ext_vector_type(4))) float;

#define B_ 8
#define H_ 384
#define W_ 512
#define HW_ (H_*W_)
#define H2_ 192
#define W2_ 256
#define H4_ 96
#define W4_ 128

#define TEMP_F 30.0f
#define HARD_Z_F 0.001f
#define EPS_F 1e-6f

// d_out element offsets (float32), in return order
#define O_IT 0
#define O_IW 4718592
#define O_V  9437184
#define O_O  11010048
#define O_GG 12582912
#define O_DG 15728640
#define O_ZT 18874368

// ---- workspace layout (bytes). Peak ~229.1 MB < 251.6 MB proven budget ----
// Splat scratch lives in [0,31.5M) and dies before h1 is written.
#define WS_ZBUF 0                       // 6,291,456
#define WS_ACC  6291456                 // 25,165,824 (ends 31,457,280)
#define WS_H1   0                       // C32 padded NHWC: 101,582,848 (ends 101,582,848)
#define WS_H2   101582848               // 101,582,848 (ends 203,165,696). e0 aliases h2.
#define WS_E0   101582848
#define WS_XIN  203165696               // 25,395,712 (ends 228,561,408)
#define WS_E1   0                       // 51,253,248 (h1 dead)
#define WS_E2   51253248                // 26,091,520 (ends 77,344,768)
#define WS_D1B  77344768                // 1 batch: 6,406,656 (ends 83,751,424)
#define WS_D0B  83751424                // 1 batch: 12,697,856 (ends 96,449,280)
#define WS_KINV 96449280                // splat-phase only (d0b written later)
#define WS_ZMAX (96449280+512)
#define WS_WT   228561408               // weights bf16: 509,952 B (ends ~229.07M)

// weight sub-offsets in ELEMENTS within WS_WT
#define WT_F1 0
#define WT_F2 3072
#define WT_F3 12288
#define WT_E0 16896
#define WT_E1 19968
#define WT_E2 38400
#define WT_D1 112128
#define WT_D0 222720
#define WT_O  250368

static __device__ __forceinline__ short f2bs(float f){
  __hip_bfloat16 h = __float2bfloat16(f);
  return *reinterpret_cast<short*>(&h);
}

// ================= splat (verified in round 4, unchanged) =================
__global__ void k_mats(const float* __restrict__ Ks, float* __restrict__ kinv){
#pragma clang fp contract(off)
  int b = threadIdx.x;
  if (b >= B_) return;
  float A[3][3]; int piv[3] = {0,1,2};
  for (int i=0;i<3;i++) for (int j=0;j<3;j++) A[i][j] = Ks[b*9 + i*3 + j];
  for (int k=0;k<3;k++){
    int p = k; float mx = fabsf(A[k][k]);
    for (int i=k+1;i<3;i++){ float v = fabsf(A[i][k]); if (v > mx){ mx = v; p = i; } }
    if (p != k){
      for (int j=0;j<3;j++){ float t = A[k][j]; A[k][j] = A[p][j]; A[p][j] = t; }
      int t = piv[k]; piv[k] = piv[p]; piv[p] = t;
    }
    for (int i=k+1;i<3;i++){
      A[i][k] = A[i][k] / A[k][k];
      for (int j=k+1;j<3;j++) A[i][j] = A[i][j] - A[i][k]*A[k][j];
    }
  }
  for (int col=0; col<3; col++){
    float y0 = (piv[0]==col) ? 1.0f : 0.0f;
    float y1 = (piv[1]==col) ? 1.0f : 0.0f;
    float y2 = (piv[2]==col) ? 1.0f : 0.0f;
    y1 = y1 - A[1][0]*y0;
    y2 = (y2 - A[2][0]*y0) - A[2][1]*y1;
    float x2 = y2 / A[2][2];
    float x1 = (y1 - A[1][2]*x2) / A[1][1];
    float x0 = ((y0 - A[0][1]*x1) - A[0][2]*x2) / A[0][0];
    kinv[b*9 + 0*3 + col] = x0;
    kinv[b*9 + 1*3 + col] = x1;
    kinv[b*9 + 2*3 + col] = x2;
  }
}

__device__ __forceinline__ void proj_f(const float* __restrict__ Ki,
                                       const float* __restrict__ T,
                                       const float* __restrict__ Q,
                                       float d, float px, float py,
                                       float& xt, float& yt, float& z){
#pragma clang fp contract(off)
  float c0 = ((Ki[0]*px + Ki[1]*py) + Ki[2]) * d;
  float c1 = ((Ki[3]*px + Ki[4]*py) + Ki[5]) * d;
  float c2 = ((Ki[6]*px + Ki[7]*py) + Ki[8]) * d;
  float X0 = ((T[0]*c0 + T[1]*c1) + T[2]*c2) + T[3];
  float X1 = ((T[4]*c0 + T[5]*c1) + T[6]*c2) + T[7];
  float X2 = ((T[8]*c0 + T[9]*c1) + T[10]*c2) + T[11];
  float p0 = (Q[0]*X0 + Q[1]*X1) + Q[2]*X2;
  float p1 = (Q[3]*X0 + Q[4]*X1) + Q[5]*X2;
  float p2 = (Q[6]*X0 + Q[7]*X1) + Q[8]*X2;
  z = p2;
  float zc = fmaxf(z, EPS_F);
  xt = p0/zc; yt = p1/zc;
}

__global__ void k_project(const float* __restrict__ Ds, const float* __restrict__ Kt,
                          const float* __restrict__ dT, const float* __restrict__ kinv,
                          unsigned* __restrict__ zmax, float* __restrict__ out){
#pragma clang fp contract(off)
  int pix = blockIdx.x*256 + threadIdx.x;
  int b = blockIdx.y;
  int y = pix / W_, x = pix % W_;
  float d = fmaxf(Ds[b*HW_ + pix], 0.001f);
  float xt, yt, z;
  proj_f(kinv + b*9, dT + b*16, Kt + b*9, d, (float)x, (float)y, xt, yt, z);
  int gi = b*HW_ + pix;
  out[O_GG + 2*gi + 0] = (2.0f*xt + 1.0f)/(float)W_ - 1.0f;
  out[O_GG + 2*gi + 1] = (2.0f*yt + 1.0f)/(float)H_ - 1.0f;
  out[O_ZT + gi] = z;
  float zi = (z > EPS_F) ? z : 0.0f;
  #pragma unroll
  for (int off=32; off; off>>=1) zi = fmaxf(zi, __shfl_down(zi, off, 64));
  __shared__ float sm[4];
  int lane = threadIdx.x & 63, wid = threadIdx.x >> 6;
  if (lane==0) sm[wid]=zi;
  __syncthreads();
  if (threadIdx.x==0){
    float m = fmaxf(fmaxf(sm[0],sm[1]), fmaxf(sm[2],sm[3]));
    atomicMax(zmax + b, __float_as_uint(m));
  }
}

__global__ void k_zbuf(const float* __restrict__ Ds, const float* __restrict__ Kt,
                       const float* __restrict__ dT, const float* __restrict__ kinv,
                       unsigned* __restrict__ zbuf){
#pragma clang fp contract(off)
  int pix = blockIdx.x*256 + threadIdx.x;
  int b = blockIdx.y;
  int y = pix / W_, x = pix % W_;
  float d = fmaxf(Ds[b*HW_ + pix], 0.001f);
  float xv, yv, z;
  proj_f(kinv + b*9, dT + b*16, Kt + b*9, d, (float)x, (float)y, xv, yv, z);
  if (!(z > EPS_F)) return;
  float x0 = floorf(xv), y0 = floorf(yv);
  unsigned zu = __float_as_uint(z);
  #pragma unroll
  for (int c=0;c<4;c++){
    float cx = x0 + (float)(c&1), cy = y0 + (float)(c>>1);
    float bw = (1.0f - fabsf(xv-cx)) * (1.0f - fabsf(yv-cy));
    if (cx>=0.f && cx<(float)W_ && cy>=0.f && cy<(float)H_ && bw>0.f){
      int flat = b*HW_ + (int)cy*W_ + (int)cx;
      atomicMin(zbuf + flat, zu);
    }
  }
}

__global__ void k_acc(const float* __restrict__ Is, const float* __restrict__ Ds,
                      const float* __restrict__ Kt, const float* __restrict__ dT,
                      const float* __restrict__ kinv,
                      const float* __restrict__ zbuf,
                      const unsigned* __restrict__ zmax,
                      float* __restrict__ acc){
#pragma clang fp contract(off)
  int pix = blockIdx.x*256+threadIdx.x;
  int b = blockIdx.y;
  int y = pix / W_, x = pix % W_;
  float d = fmaxf(Ds[b*HW_ + pix], 0.001f);
  float xv, yv, z;
  proj_f(kinv + b*9, dT + b*16, Kt + b*9, d, (float)x, (float)y, xv, yv, z);
  if (!(z > EPS_F)) return;
  float zm = __uint_as_float(zmax[b]) + EPS_F;
  float q = z / zm;
  float w = expf((-TEMP_F) * q);
  float r = Is[(b*3+0)*HW_+pix], g = Is[(b*3+1)*HW_+pix], bl = Is[(b*3+2)*HW_+pix];
  float x0 = floorf(xv), y0 = floorf(yv);
  #pragma unroll
  for (int c=0;c<4;c++){
    float cx = x0 + (float)(c&1), cy = y0 + (float)(c>>1);
    float bw = (1.0f - fabsf(xv-cx)) * (1.0f - fabsf(yv-cy));
    if (cx>=0.f && cx<(float)W_ && cy>=0.f && cy<(float)H_ && bw>0.f){
      int flat = b*HW_ + (int)cy*W_ + (int)cx;
      if (z <= zbuf[flat] + HARD_Z_F){
        float wt = bw*w;
        atomicAdd(acc + flat*4 + 0, wt*r);
        atomicAdd(acc + flat*4 + 1, wt*g);
        atomicAdd(acc + flat*4 + 2, wt*bl);
        atomicAdd(acc + flat*4 + 3, wt);
      }
    }
  }
}

__global__ void k_norm(const float* __restrict__ acc, float* __restrict__ out){
#pragma clang fp contract(off)
  int pix = blockIdx.x*256+threadIdx.x;
  int b = blockIdx.y;
  int gi = b*HW_+pix;
  float4 a = reinterpret_cast<const float4*>(acc)[gi];
  float den = a.w;
  float denc = fmaxf(den, EPS_F);
  bool on = den > EPS_F;
  out[O_IW + (b*3+0)*HW_+pix] = on ? a.x/denc : 0.0f;
  out[O_IW + (b*3+1)*HW_+pix] = on ? a.y/denc : 0.0f;
  out[O_IW + (b*3+2)*HW_+pix] = on ? a.z/denc : 0.0f;
  out[O_V + gi] = fminf(fmaxf(den, 0.0f), 1.0f);
}

// ================= NHWC packers =================
__global__ void k_packF(const float* __restrict__ Is, const float* __restrict__ Ds,
                        const float* __restrict__ out, bf16* __restrict__ xin){
  int pix = blockIdx.x*256+threadIdx.x;
  int b = blockIdx.y;
  int y = pix / W_, x = pix % W_;
  int gi = b*HW_+pix;
  bf16x8 v;
  v[0] = f2bs(Is[(b*3+0)*HW_+pix]);
  v[1] = f2bs(Is[(b*3+1)*HW_+pix]);
  v[2] = f2bs(Is[(b*3+2)*HW_+pix]);
  v[3] = f2bs(Ds[gi]);
  v[4] = f2bs(out[O_V + gi]);
  v[5] = 0; v[6] = 0; v[7] = 0;
  *reinterpret_cast<bf16x8*>(xin + (((b*(H_+2) + y+1))*(W_+2) + x+1)*8) = v;
}

__global__ void k_packU(const float* __restrict__ out, bf16* __restrict__ xin){
  int pix = blockIdx.x*256+threadIdx.x;
  int b = blockIdx.y;
  int y = pix / W_, x = pix % W_;
  int gi = b*HW_+pix;
  bf16x8 v;
  v[0] = f2bs(out[O_IW + (b*3+0)*HW_+pix]);
  v[1] = f2bs(out[O_IW + (b*3+1)*HW_+pix]);
  v[2] = f2bs(out[O_IW + (b*3+2)*HW_+pix]);
  v[3] = f2bs(out[O_V + gi]);
  v[4] = f2bs(out[O_O + gi]);
  v[5] = 0; v[6] = 0; v[7] = 0;
  *reinterpret_cast<bf16x8*>(xin + (((b*(H_+2) + y+1))*(W_+2) + x+1)*8) = v;
}

// ================= weight repack: (Cout,Cin,3,3) f32 -> (CoutP, KP) bf16, k = tap*CPAD + c ====
template<int CIN, int CPAD, int COUT, int COUTP>
__global__ void k_wprep(const float* __restrict__ src, bf16* __restrict__ dst){
  constexpr int KP = ((9*CPAD + 31)/32)*32;
  int i = blockIdx.x*256 + threadIdx.x;
  if (i >= COUTP*KP) return;
  int co = i / KP, k = i - co*KP;
  int tap = k / CPAD, c = k - tap*CPAD;
  float v = 0.0f;
  if (co < COUT && tap < 9 && c < CIN)
    v = src[((co*CIN + c)*3 + tap/3)*3 + (tap%3)];
  dst[i] = __float2bfloat16(v);
}

// ================= MFMA implicit-GEMM 3x3 conv ========================
// Padded NHWC in/out (1-px zero halo). Optional up2 source inA for channels [0,CA).
// Block: 4 waves x 32 px = 128 output px (one row), CT=16*NN couts.
// ACT: 0 = ReLU -> bf16 outP; 1 = flow head (tanh,tanh,sigmoid -> d_out); 2 = IT head (f32 -> d_out)
template<int CPAD, int CA, int STRIDE, int NN, int ACT, int COUT>
__global__ __launch_bounds__(256) void k_gconv(
    const bf16* __restrict__ inB, const bf16* __restrict__ inA,
    const bf16* __restrict__ wt, const float* __restrict__ bias,
    bf16* __restrict__ outP, float* __restrict__ out2,
    int HpB, int WpB, int HpA, int WpA, int HpO, int WpO, int bo2)
{
  constexpr int CB = CPAD - CA;
  constexpr int KP = ((9*CPAD + 31)/32)*32;
  constexpr int CT = 16*NN;
  int lane = threadIdx.x & 63;
  int w = threadIdx.x >> 6;
  int arow = lane & 15, kg = lane >> 4;
  int y = blockIdx.y;
  int zz = blockIdx.z;
  int b = zz / (COUT/CT);
  int co0 = (zz - b*(COUT/CT)) * CT;
  int px0 = blockIdx.x*128 + w*32;

  f32x4 acc[2][NN];
  #pragma unroll
  for (int m=0;m<2;m++)
    #pragma unroll
    for (int n=0;n<NN;n++) acc[m][n] = (f32x4){0.f,0.f,0.f,0.f};

  for (int ks=0; ks < KP/32; ks++){
    int k = ks*32 + kg*8;
    int tap = k / CPAD;
    int c = k - tap*CPAD;
    if (tap >= 9) tap = 0;                 // zero-weight pad region; addr stays valid
    int kyy = tap/3, kx = tap - (tap/3)*3;

    bf16x8 a[2];
    #pragma unroll
    for (int m=0;m<2;m++){
      int px = px0 + m*16 + arow;
      const bf16* src;
      if (CA > 0 && c < CA){
        int yy = y + kyy - 1, xx = px + kx - 1;
        int yu = (yy >> 1) + 1, xu = (xx >> 1) + 1;
        src = inA + ((b*HpA + yu)*WpA + xu)*CA + c;
      } else {
        int yp, xp;
        if (STRIDE==1){ yp = y + kyy; xp = px + kx; }
        else          { yp = 2*y + kyy + 1; xp = 2*px + kx + 1; }
        src = inB + ((b*HpB + yp)*WpB + xp)*CB + (c - CA);
      }
      a[m] = *reinterpret_cast<const bf16x8*>(src);
    }
    bf16x8 bb[NN];
    #pragma unroll
    for (int n=0;n<NN;n++){
      int co = co0 + n*16 + arow;
      bb[n] = *reinterpret_cast<const bf16x8*>(wt + co*KP + ks*32 + kg*8);
    }
    #pragma unroll
    for (int m=0;m<2;m++)
      #pragma unroll
      for (int n=0;n<NN;n++)
        acc[m][n] = __builtin_amdgcn_mfma_f32_16x16x32_bf16(a[m], bb[n], acc[m][n], 0,0,0);
  }

  // epilogue: C/D layout col=lane&15 (cout), row=(lane>>4)*4+reg (pixel)
  int bo = b + bo2;
  #pragma unroll
  for (int n=0;n<NN;n++){
    int co = co0 + n*16 + (lane & 15);
    float bv;
    if (ACT==0) bv = bias[co];
    else        bv = (co < 3) ? bias[co] : 0.0f;
    #pragma unroll
    for (int m=0;m<2;m++){
      #pragma unroll
      for (int r=0;r<4;r++){
        int px = px0 + m*16 + (lane>>4)*4 + r;
        float v = acc[m][n][r] + bv;
        if (ACT==0){
          v = fmaxf(v, 0.0f);
          outP[((b*HpO + y+1)*WpO + px+1)*COUT + co] = __float2bfloat16(v);
        } else if (ACT==1){
          if (co < 2)       out2[O_DG + (bo*2+co)*HW_ + y*W_ + px] = tanhf(v);
          else if (co == 2) out2[O_O + bo*HW_ + y*W_ + px] = 1.0f/(1.0f+expf(-v));
        } else {
          if (co < 3)       out2[O_IT + (bo*3+co)*HW_ + y*W_ + px] = v;
        }
      }
    }
  }
}

// ================= launch =================
extern "C" void kernel_launch(void* const* d_in, const int* in_sizes, int n_in,
                              void* d_out, int out_size, void* d_ws, size_t ws_size,
                              hipStream_t stream){
  const float* Is = (const float*)d_in[0];
  const float* Ds = (const float*)d_in[1];
  const float* Ks = (const float*)d_in[2];
  const float* Kt = (const float*)d_in[3];
  const float* dT = (const float*)d_in[4];
  const float* fw1=(const float*)d_in[5];  const float* fb1=(const float*)d_in[6];
  const float* fw2=(const float*)d_in[7];  const float* fb2=(const float*)d_in[8];
  const float* fw3=(const float*)d_in[9];  const float* fb3=(const float*)d_in[10];
  const float* we0=(const float*)d_in[11]; const float* be0=(const float*)d_in[12];
  const float* we1=(const float*)d_in[13]; const float* be1=(const float*)d_in[14];
  const float* we2=(const float*)d_in[15]; const float* be2=(const float*)d_in[16];
  const float* wd1=(const float*)d_in[17]; const float* bd1=(const float*)d_in[18];
  const float* wd0=(const float*)d_in[19]; const float* bd0=(const float*)d_in[20];
  const float* wo =(const float*)d_in[21]; const float* bo =(const float*)d_in[22];
  float* out = (float*)d_out;
  char* ws = (char*)d_ws;

  float*    kinv = (float*)(ws + WS_KINV);
  unsigned* zmax = (unsigned*)(ws + WS_ZMAX);
  unsigned* zbuf = (unsigned*)(ws + WS_ZBUF);
  float*    acc  = (float*)(ws + WS_ACC);
  bf16* xin = (bf16*)(ws + WS_XIN);
  bf16* h1  = (bf16*)(ws + WS_H1);
  bf16* h2  = (bf16*)(ws + WS_H2);
  bf16* e0  = (bf16*)(ws + WS_E0);
  bf16* e1  = (bf16*)(ws + WS_E1);
  bf16* e2  = (bf16*)(ws + WS_E2);
  bf16* d1b = (bf16*)(ws + WS_D1B);
  bf16* d0b = (bf16*)(ws + WS_D0B);
  bf16* wtb = (bf16*)(ws + WS_WT);

  // ---- weight repack (small) ----
  k_wprep<5,8,32,32>    <<<12, 256, 0, stream>>>(fw1, wtb + WT_F1);
  k_wprep<32,32,32,32>  <<<36, 256, 0, stream>>>(fw2, wtb + WT_F2);
  k_wprep<32,32,3,16>   <<<18, 256, 0, stream>>>(fw3, wtb + WT_F3);
  k_wprep<5,8,32,32>    <<<12, 256, 0, stream>>>(we0, wtb + WT_E0);
  k_wprep<32,32,64,64>  <<<72, 256, 0, stream>>>(we1, wtb + WT_E1);
  k_wprep<64,64,128,128><<<288,256, 0, stream>>>(we2, wtb + WT_E2);
  k_wprep<192,192,64,64><<<432,256, 0, stream>>>(wd1, wtb + WT_D1);
  k_wprep<96,96,32,32>  <<<108,256, 0, stream>>>(wd0, wtb + WT_D0);
  k_wprep<32,32,3,16>   <<<18, 256, 0, stream>>>(wo,  wtb + WT_O);

  // ---- splat ----
  hipMemsetAsync(zmax, 0, 32, stream);
  hipMemsetAsync(zbuf, 0x7f, (size_t)B_*HW_*4, stream);
  hipMemsetAsync(acc, 0, (size_t)B_*HW_*4*4, stream);
  k_mats<<<1, 64, 0, stream>>>(Ks, kinv);
  dim3 gpix(HW_/256, B_);
  k_project<<<gpix, 256, 0, stream>>>(Ds, Kt, dT, kinv, zmax, out);
  k_zbuf<<<gpix, 256, 0, stream>>>(Ds, Kt, dT, kinv, zbuf);
  k_acc<<<gpix, 256, 0, stream>>>(Is, Ds, Kt, dT, kinv, (const float*)zbuf, zmax, acc);
  k_norm<<<gpix, 256, 0, stream>>>(acc, out);

  const int szXIN = B_*(H_+2)*(W_+2)*8*2;
  const int szC32 = B_*(H_+2)*(W_+2)*32*2;
  const int szE1  = B_*(H2_+2)*(W2_+2)*64*2;
  const int szE2  = B_*(H4_+2)*(W4_+2)*128*2;
  const int szD1b = (H2_+2)*(W2_+2)*64*2;
  const int szD0b = (H_+2)*(W_+2)*32*2;

  // ---- flow net ----
  hipMemsetAsync(xin, 0, szXIN, stream);
  k_packF<<<gpix, 256, 0, stream>>>(Is, Ds, out, xin);
  hipMemsetAsync(h1, 0, szC32, stream);
  k_gconv<8,0,1,2,0,32><<<dim3(4,384,8), 256, 0, stream>>>(
      xin, nullptr, wtb+WT_F1, fb1, h1, nullptr, H_+2, W_+2, 0,0, H_+2, W_+2, 0);
  hipMemsetAsync(h2, 0, szC32, stream);
  k_gconv<32,0,1,2,0,32><<<dim3(4,384,8), 256, 0, stream>>>(
      h1, nullptr, wtb+WT_F2, fb2, h2, nullptr, H_+2, W_+2, 0,0, H_+2, W_+2, 0);
  k_gconv<32,0,1,1,1,16><<<dim3(4,384,8), 256, 0, stream>>>(
      h2, nullptr, wtb+WT_F3, fb3, nullptr, out, H_+2, W_+2, 0,0, 0,0, 0);

  // ---- unet encoder ----
  k_packU<<<gpix, 256, 0, stream>>>(out, xin);
  k_gconv<8,0,1,2,0,32><<<dim3(4,384,8), 256, 0, stream>>>(
      xin, nullptr, wtb+WT_E0, be0, e0, nullptr, H_+2, W_+2, 0,0, H_+2, W_+2, 0);
  hipMemsetAsync(e1, 0, szE1, stream);
  k_gconv<32,0,2,2,0,64><<<dim3(2,192,16), 256, 0, stream>>>(
      e0, nullptr, wtb+WT_E1, be1, e1, nullptr, H_+2, W_+2, 0,0, H2_+2, W2_+2, 0);
  hipMemsetAsync(e2, 0, szE2, stream);
  k_gconv<64,0,2,2,0,128><<<dim3(1,96,32), 256, 0, stream>>>(
      e1, nullptr, wtb+WT_E2, be2, e2, nullptr, H2_+2, W2_+2, 0,0, H4_+2, W4_+2, 0);

  // ---- decoder, per-batch (memory budget) ----
  hipMemsetAsync(d1b, 0, szD1b, stream);
  hipMemsetAsync(d0b, 0, szD0b, stream);
  for (int b = 0; b < B_; b++){
    const bf16* e1b = e1 + (size_t)b*(H2_+2)*(W2_+2)*64;
    const bf16* e2b = e2 + (size_t)b*(H4_+2)*(W4_+2)*128;
    const bf16* e0b = e0 + (size_t)b*(H_+2)*(W_+2)*32;
    k_gconv<192,128,1,2,0,64><<<dim3(2,192,2), 256, 0, stream>>>(
        e1b, e2b, wtb+WT_D1, bd1, d1b, nullptr, H2_+2, W2_+2, H4_+2, W4_+2, H2_+2, W2_+2, 0);
    k_gconv<96,64,1,2,0,32><<<dim3(4,384,1), 256, 0, stream>>>(
        e0b, d1b, wtb+WT_D0, bd0, d0b, nullptr, H_+2, W_+2, H2_+2, W2_+2, H_+2, W_+2, 0);
    k_gconv<32,0,1,1,2,16><<<dim3(4,384,1), 256, 0, stream>>>(
        d0b, nullptr, wtb+WT_O, bo, nullptr, out, H_+2, W_+2, 0,0, 0,0, b);
  }
}

// Round 6
// 1581.890 us; speedup vs baseline: 36.8955x; 1.2406x over previous
//
#include <hip/hip_runtime.h>
#include <hip/hip_bf16.h>
#include <math.h>

using bf16 = __hip_bfloat16;
using bf16x8 = __attribute__((ext_vector_type(8))) short;
using f32x4  = __attribute__((ext_vector_type(4))) float;

#define B_ 8
#define H_ 384
#define W_ 512
#define HW_ (H_*W_)
#define H2_ 192
#define W2_ 256
#define H4_ 96
#define W4_ 128

#define TEMP_F 30.0f
#define HARD_Z_F 0.001f
#define EPS_F 1e-6f

// d_out element offsets (float32), in return order
#define O_IT 0
#define O_IW 4718592
#define O_V  9437184
#define O_O  11010048
#define O_GG 12582912
#define O_DG 15728640
#define O_ZT 18874368

// ---- workspace layout (bytes), lifetime-multiplexed; peak ~230.7 MB < 251.66 MB proven ----
#define WS_ZBUF0 0
#define WS_ZBUF1 6291456
#define WS_ACC0  12582912
#define WS_ACC1  37748736          // ends 62,914,560 (splat phase only)
#define WS_H1    0                 // 101,582,848 (flow; after splat dead)
#define WS_H2    101582848         // ends 203,165,696
#define WS_XIN   203165696         // 25,395,712 (ends 228,561,408)
#define WS_E0    0                 // ends 101,582,848 (h1 dead)
#define WS_E1    101582848         // 51,253,248 (ends 152,836,096; h2 dead)
#define WS_E2    152836096         // 26,091,520 (ends 178,927,616)
#define WS_D1    178927616         // 51,253,248 (ends 230,180,864; xin dead)
#define WS_D0H   101582848         // 50,791,424 half-batch (e1 dead after d1)
#define WS_WT    230180864         // 509,952
#define WS_KINV  230690816
#define WS_ZMAX  230691328

// weight sub-offsets in ELEMENTS within WS_WT
#define WT_F1 0
#define WT_F2 3072
#define WT_F3 12288
#define WT_E0 16896
#define WT_E1 19968
#define WT_E2 38400
#define WT_D1 112128
#define WT_D0 222720
#define WT_O  250368

static __device__ __forceinline__ short f2bs(float f){
  __hip_bfloat16 h = __float2bfloat16(f);
  return *reinterpret_cast<short*>(&h);
}

// ================= splat =================
__global__ void k_mats(const float* __restrict__ Ks, float* __restrict__ kinv){
#pragma clang fp contract(off)
  int b = threadIdx.x;
  if (b >= B_) return;
  float A[3][3]; int piv[3] = {0,1,2};
  for (int i=0;i<3;i++) for (int j=0;j<3;j++) A[i][j] = Ks[b*9 + i*3 + j];
  for (int k=0;k<3;k++){
    int p = k; float mx = fabsf(A[k][k]);
    for (int i=k+1;i<3;i++){ float v = fabsf(A[i][k]); if (v > mx){ mx = v; p = i; } }
    if (p != k){
      for (int j=0;j<3;j++){ float t = A[k][j]; A[k][j] = A[p][j]; A[p][j] = t; }
      int t = piv[k]; piv[k] = piv[p]; piv[p] = t;
    }
    for (int i=k+1;i<3;i++){
      A[i][k] = A[i][k] / A[k][k];
      for (int j=k+1;j<3;j++) A[i][j] = A[i][j] - A[i][k]*A[k][j];
    }
  }
  for (int col=0; col<3; col++){
    float y0 = (piv[0]==col) ? 1.0f : 0.0f;
    float y1 = (piv[1]==col) ? 1.0f : 0.0f;
    float y2 = (piv[2]==col) ? 1.0f : 0.0f;
    y1 = y1 - A[1][0]*y0;
    y2 = (y2 - A[2][0]*y0) - A[2][1]*y1;
    float x2 = y2 / A[2][2];
    float x1 = (y1 - A[1][2]*x2) / A[1][1];
    float x0 = ((y0 - A[0][1]*x1) - A[0][2]*x2) / A[0][0];
    kinv[b*9 + 0*3 + col] = x0;
    kinv[b*9 + 1*3 + col] = x1;
    kinv[b*9 + 2*3 + col] = x2;
  }
}

__device__ __forceinline__ void proj_f(const float* __restrict__ Ki,
                                       const float* __restrict__ T,
                                       const float* __restrict__ Q,
                                       float d, float px, float py,
                                       float& xt, float& yt, float& z){
#pragma clang fp contract(off)
  float c0 = ((Ki[0]*px + Ki[1]*py) + Ki[2]) * d;
  float c1 = ((Ki[3]*px + Ki[4]*py) + Ki[5]) * d;
  float c2 = ((Ki[6]*px + Ki[7]*py) + Ki[8]) * d;
  float X0 = ((T[0]*c0 + T[1]*c1) + T[2]*c2) + T[3];
  float X1 = ((T[4]*c0 + T[5]*c1) + T[6]*c2) + T[7];
  float X2 = ((T[8]*c0 + T[9]*c1) + T[10]*c2) + T[11];
  float p0 = (Q[0]*X0 + Q[1]*X1) + Q[2]*X2;
  float p1 = (Q[3]*X0 + Q[4]*X1) + Q[5]*X2;
  float p2 = (Q[6]*X0 + Q[7]*X1) + Q[8]*X2;
  z = p2;
  float zc = fmaxf(z, EPS_F);
  xt = p0/zc; yt = p1/zc;
}

// fused: grid_geo/zt outputs + zmax reduce + z-buffer atomicMin (2 copies by block parity)
__global__ void k_proj(const float* __restrict__ Ds, const float* __restrict__ Kt,
                       const float* __restrict__ dT, const float* __restrict__ kinv,
                       unsigned* __restrict__ zmax,
                       unsigned* __restrict__ zbuf0, unsigned* __restrict__ zbuf1,
                       float* __restrict__ out){
#pragma clang fp contract(off)
  int pix = blockIdx.x*256 + threadIdx.x;
  int b = blockIdx.y;
  int y = pix / W_, x = pix % W_;
  float d = fmaxf(Ds[b*HW_ + pix], 0.001f);
  float xv, yv, z;
  proj_f(kinv + b*9, dT + b*16, Kt + b*9, d, (float)x, (float)y, xv, yv, z);
  int gi = b*HW_ + pix;
  out[O_GG + 2*gi + 0] = (2.0f*xv + 1.0f)/(float)W_ - 1.0f;
  out[O_GG + 2*gi + 1] = (2.0f*yv + 1.0f)/(float)H_ - 1.0f;
  out[O_ZT + gi] = z;
  float zi = (z > EPS_F) ? z : 0.0f;
  #pragma unroll
  for (int off=32; off; off>>=1) zi = fmaxf(zi, __shfl_down(zi, off, 64));
  __shared__ float sm[4];
  int lane = threadIdx.x & 63, wid = threadIdx.x >> 6;
  if (lane==0) sm[wid]=zi;
  __syncthreads();
  if (threadIdx.x==0){
    float m = fmaxf(fmaxf(sm[0],sm[1]), fmaxf(sm[2],sm[3]));
    atomicMax(zmax + b, __float_as_uint(m));
  }
  if (z > EPS_F){
    unsigned* zb = (blockIdx.x & 1) ? zbuf1 : zbuf0;
    float x0 = floorf(xv), y0 = floorf(yv);
    unsigned zu = __float_as_uint(z);
    #pragma unroll
    for (int c=0;c<4;c++){
      float cx = x0 + (float)(c&1), cy = y0 + (float)(c>>1);
      float bw = (1.0f - fabsf(xv-cx)) * (1.0f - fabsf(yv-cy));
      if (cx>=0.f && cx<(float)W_ && cy>=0.f && cy<(float)H_ && bw>0.f){
        int flat = b*HW_ + (int)cy*W_ + (int)cx;
        atomicMin(zb + flat, zu);
      }
    }
  }
}

__global__ void k_zmerge(unsigned* __restrict__ z0, const unsigned* __restrict__ z1){
  int i = blockIdx.x*256 + threadIdx.x;
  uint4 a = reinterpret_cast<uint4*>(z0)[i];
  uint4 c = reinterpret_cast<const uint4*>(z1)[i];
  a.x = min(a.x, c.x); a.y = min(a.y, c.y); a.z = min(a.z, c.z); a.w = min(a.w, c.w);
  reinterpret_cast<uint4*>(z0)[i] = a;
}

__global__ void k_acc(const float* __restrict__ Is, const float* __restrict__ Ds,
                      const float* __restrict__ Kt, const float* __restrict__ dT,
                      const float* __restrict__ kinv,
                      const float* __restrict__ zbuf,
                      const unsigned* __restrict__ zmax,
                      float* __restrict__ acc0, float* __restrict__ acc1){
#pragma clang fp contract(off)
  int pix = blockIdx.x*256+threadIdx.x;
  int b = blockIdx.y;
  int y = pix / W_, x = pix % W_;
  float d = fmaxf(Ds[b*HW_ + pix], 0.001f);
  float xv, yv, z;
  proj_f(kinv + b*9, dT + b*16, Kt + b*9, d, (float)x, (float)y, xv, yv, z);
  if (!(z > EPS_F)) return;
  float* acc = (blockIdx.x & 1) ? acc1 : acc0;
  float zm = __uint_as_float(zmax[b]) + EPS_F;
  float q = z / zm;
  float w = expf((-TEMP_F) * q);
  float r = Is[(b*3+0)*HW_+pix], g = Is[(b*3+1)*HW_+pix], bl = Is[(b*3+2)*HW_+pix];
  float x0 = floorf(xv), y0 = floorf(yv);
  #pragma unroll
  for (int c=0;c<4;c++){
    float cx = x0 + (float)(c&1), cy = y0 + (float)(c>>1);
    float bw = (1.0f - fabsf(xv-cx)) * (1.0f - fabsf(yv-cy));
    if (cx>=0.f && cx<(float)W_ && cy>=0.f && cy<(float)H_ && bw>0.f){
      int flat = b*HW_ + (int)cy*W_ + (int)cx;
      if (z <= zbuf[flat] + HARD_Z_F){
        float wt = bw*w;
        atomicAdd(acc + flat*4 + 0, wt*r);
        atomicAdd(acc + flat*4 + 1, wt*g);
        atomicAdd(acc + flat*4 + 2, wt*bl);
        atomicAdd(acc + flat*4 + 3, wt);
      }
    }
  }
}

__global__ void k_norm(const float* __restrict__ acc0, const float* __restrict__ acc1,
                       float* __restrict__ out){
#pragma clang fp contract(off)
  int pix = blockIdx.x*256+threadIdx.x;
  int b = blockIdx.y;
  int gi = b*HW_+pix;
  float4 a = reinterpret_cast<const float4*>(acc0)[gi];
  float4 c = reinterpret_cast<const float4*>(acc1)[gi];
  float nx = a.x + c.x, ny = a.y + c.y, nz = a.z + c.z;
  float den = a.w + c.w;
  float denc = fmaxf(den, EPS_F);
  bool on = den > EPS_F;
  out[O_IW + (b*3+0)*HW_+pix] = on ? nx/denc : 0.0f;
  out[O_IW + (b*3+1)*HW_+pix] = on ? ny/denc : 0.0f;
  out[O_IW + (b*3+2)*HW_+pix] = on ? nz/denc : 0.0f;
  out[O_V + gi] = fminf(fmaxf(den, 0.0f), 1.0f);
}

// ================= NHWC packers =================
__global__ void k_packF(const float* __restrict__ Is, const float* __restrict__ Ds,
                        const float* __restrict__ out, bf16* __restrict__ xin){
  int pix = blockIdx.x*256+threadIdx.x;
  int b = blockIdx.y;
  int y = pix / W_, x = pix % W_;
  int gi = b*HW_+pix;
  bf16x8 v;
  v[0] = f2bs(Is[(b*3+0)*HW_+pix]);
  v[1] = f2bs(Is[(b*3+1)*HW_+pix]);
  v[2] = f2bs(Is[(b*3+2)*HW_+pix]);
  v[3] = f2bs(Ds[gi]);
  v[4] = f2bs(out[O_V + gi]);
  v[5] = 0; v[6] = 0; v[7] = 0;
  *reinterpret_cast<bf16x8*>(xin + (((b*(H_+2) + y+1))*(W_+2) + x+1)*8) = v;
}

__global__ void k_packU(const float* __restrict__ out, bf16* __restrict__ xin){
  int pix = blockIdx.x*256+threadIdx.x;
  int b = blockIdx.y;
  int y = pix / W_, x = pix % W_;
  int gi = b*HW_+pix;
  bf16x8 v;
  v[0] = f2bs(out[O_IW + (b*3+0)*HW_+pix]);
  v[1] = f2bs(out[O_IW + (b*3+1)*HW_+pix]);
  v[2] = f2bs(out[O_IW + (b*3+2)*HW_+pix]);
  v[3] = f2bs(out[O_V + gi]);
  v[4] = f2bs(out[O_O + gi]);
  v[5] = 0; v[6] = 0; v[7] = 0;
  *reinterpret_cast<bf16x8*>(xin + (((b*(H_+2) + y+1))*(W_+2) + x+1)*8) = v;
}

// halo zeroing: border ring of a padded NHWC buffer
template<int C>
__global__ void k_halo(bf16* __restrict__ buf, int Hp, int Wp, int nb){
  int nh = 2*Wp + 2*(Hp-2);
  int i = blockIdx.x*256 + threadIdx.x;
  int total = nb*nh*(C/8);
  if (i >= total) return;
  int cv = i % (C/8); int hp = (i / (C/8)) % nh; int b = i / ((C/8)*nh);
  int y, x;
  if (hp < Wp){ y = 0; x = hp; }
  else if (hp < 2*Wp){ y = Hp-1; x = hp - Wp; }
  else { int r = hp - 2*Wp; y = 1 + (r>>1); x = (r&1) ? Wp-1 : 0; }
  bf16x8 zv = {0,0,0,0,0,0,0,0};
  *reinterpret_cast<bf16x8*>(buf + (((size_t)b*Hp + y)*Wp + x)*C + cv*8) = zv;
}

// ================= weight repack =================
template<int CIN, int CPAD, int COUT, int COUTP>
__global__ void k_wprep(const float* __restrict__ src, bf16* __restrict__ dst){
  constexpr int KP = ((9*CPAD + 31)/32)*32;
  int i = blockIdx.x*256 + threadIdx.x;
  if (i >= COUTP*KP) return;
  int co = i / KP, k = i - co*KP;
  int tap = k / CPAD, c = k - tap*CPAD;
  float v = 0.0f;
  if (co < COUT && tap < 9 && c < CIN)
    v = src[((co*CIN + c)*3 + tap/3)*3 + (tap%3)];
  dst[i] = __float2bfloat16(v);
}

// ================= MFMA implicit-GEMM 3x3 conv ========================
// ACT: 0 = ReLU -> bf16 outP; 1 = flow head; 2 = IT head
template<int CPAD, int CA, int STRIDE, int MM, int NN, int ACT, int COUT>
__global__ __launch_bounds__(256) void k_gconv(
    const bf16* __restrict__ inB, const bf16* __restrict__ inA,
    const bf16* __restrict__ wt, const float* __restrict__ bias,
    bf16* __restrict__ outP, float* __restrict__ out2,
    int HpB, int WpB, int HpA, int WpA, int HpO, int WpO, int bo2)
{
  constexpr int CB = CPAD - CA;
  constexpr int KP = ((9*CPAD + 31)/32)*32;
  constexpr int NSTEP = KP/32;
  constexpr int CT = 16*NN;
  constexpr int NCO = COUT/CT;
  int lane = threadIdx.x & 63;
  int w = threadIdx.x >> 6;
  int arow = lane & 15, kg = lane >> 4;
  int y = blockIdx.y;
  int zz = blockIdx.z;
  int b = zz / NCO;
  int co0 = (zz - b*NCO) * CT;
  int px0 = blockIdx.x*(64*MM) + w*(16*MM);

  f32x4 acc[MM][NN];
  #pragma unroll
  for (int m=0;m<MM;m++)
    #pragma unroll
    for (int n=0;n<NN;n++) acc[m][n] = (f32x4){0.f,0.f,0.f,0.f};

  int laneW = arow*KP + kg*8;
  const bf16* wbase = wt + co0*KP;

  if constexpr (CPAD >= 32){
    // 32 | CPAD: each 32-wide k-chunk has uniform tap & c-block -> scalar addressing
    int laneB[MM];
    int lamA[MM][3];
    #pragma unroll
    for (int m=0;m<MM;m++){
      int px = px0 + m*16 + arow;
      laneB[m] = (STRIDE==1 ? px : 2*px)*CB + kg*8;
      if constexpr (CA > 0){
        #pragma unroll
        for (int kx=0;kx<3;kx++)
          lamA[m][kx] = (((px + kx - 1) >> 1) + 1)*CA + kg*8;
      }
    }
    for (int ks=0; ks<NSTEP; ks++){
      int kk0 = ks*32;
      int tap = kk0 / CPAD;
      int c0 = kk0 - tap*CPAD;
      int kyy = tap/3, kx = tap - kyy*3;
      bf16x8 a[MM];
      bool isA = false;
      if constexpr (CA > 0) isA = (c0 < CA);
      if (isA){
        if constexpr (CA > 0){
          int yu = ((y + kyy - 1) >> 1) + 1;
          int sA = (b*HpA + yu)*WpA*CA + c0;
          #pragma unroll
          for (int m=0;m<MM;m++){
            int la = (kx==0) ? lamA[m][0] : ((kx==1) ? lamA[m][1] : lamA[m][2]);
            a[m] = *reinterpret_cast<const bf16x8*>(inA + sA + la);
          }
        }
      } else {
        int sB = (STRIDE==1)
          ? ((b*HpB + y + kyy)*WpB + kx)*CB + (c0 - CA)
          : ((b*HpB + 2*y + kyy + 1)*WpB + kx + 1)*CB + (c0 - CA);
        #pragma unroll
        for (int m=0;m<MM;m++)
          a[m] = *reinterpret_cast<const bf16x8*>(inB + sB + laneB[m]);
      }
      bf16x8 bb[NN];
      #pragma unroll
      for (int n=0;n<NN;n++)
        bb[n] = *reinterpret_cast<const bf16x8*>(wbase + n*16*KP + laneW + kk0);
      #pragma unroll
      for (int m=0;m<MM;m++)
        #pragma unroll
        for (int n=0;n<NN;n++)
          acc[m][n] = __builtin_amdgcn_mfma_f32_16x16x32_bf16(a[m], bb[n], acc[m][n], 0,0,0);
    }
  } else {
    // CPAD==8 (xin layers): per-lane tap, 3 k-steps
    for (int ks=0; ks<NSTEP; ks++){
      int k = ks*32 + kg*8;
      int tap = k >> 3;
      if (tap >= 9) tap = 0;               // zero-weight pad region
      int kyy = tap/3, kx = tap - (tap/3)*3;
      bf16x8 a[MM];
      #pragma unroll
      for (int m=0;m<MM;m++){
        int px = px0 + m*16 + arow;
        a[m] = *reinterpret_cast<const bf16x8*>(inB + ((b*HpB + y + kyy)*WpB + px + kx)*8);
      }
      bf16x8 bb[NN];
      #pragma unroll
      for (int n=0;n<NN;n++)
        bb[n] = *reinterpret_cast<const bf16x8*>(wbase + n*16*KP + laneW + ks*32);
      #pragma unroll
      for (int m=0;m<MM;m++)
        #pragma unroll
        for (int n=0;n<NN;n++)
          acc[m][n] = __builtin_amdgcn_mfma_f32_16x16x32_bf16(a[m], bb[n], acc[m][n], 0,0,0);
    }
  }

  // epilogue: C/D layout col=lane&15 (cout), row=(lane>>4)*4+reg (pixel)
  int bo = b + bo2;
  #pragma unroll
  for (int n=0;n<NN;n++){
    int co = co0 + n*16 + (lane & 15);
    float bv;
    if (ACT==0) bv = bias[co];
    else        bv = (co < 3) ? bias[co] : 0.0f;
    #pragma unroll
    for (int m=0;m<MM;m++){
      #pragma unroll
      for (int r=0;r<4;r++){
        int px = px0 + m*16 + (lane>>4)*4 + r;
        float v = acc[m][n][r] + bv;
        if (ACT==0){
          v = fmaxf(v, 0.0f);
          outP[((b*HpO + y+1)*WpO + px+1)*COUT + co] = __float2bfloat16(v);
        } else if (ACT==1){
          if (co < 2)       out2[O_DG + (bo*2+co)*HW_ + y*W_ + px] = tanhf(v);
          else if (co == 2) out2[O_O + bo*HW_ + y*W_ + px] = 1.0f/(1.0f+expf(-v));
        } else {
          if (co < 3)       out2[O_IT + (bo*3+co)*HW_ + y*W_ + px] = v;
        }
      }
    }
  }
}

// ================= launch =================
extern "C" void kernel_launch(void* const* d_in, const int* in_sizes, int n_in,
                              void* d_out, int out_size, void* d_ws, size_t ws_size,
                              hipStream_t stream){
  const float* Is = (const float*)d_in[0];
  const float* Ds = (const float*)d_in[1];
  const float* Ks = (const float*)d_in[2];
  const float* Kt = (const float*)d_in[3];
  const float* dT = (const float*)d_in[4];
  const float* fw1=(const float*)d_in[5];  const float* fb1=(const float*)d_in[6];
  const float* fw2=(const float*)d_in[7];  const float* fb2=(const float*)d_in[8];
  const float* fw3=(const float*)d_in[9];  const float* fb3=(const float*)d_in[10];
  const float* we0=(const float*)d_in[11]; const float* be0=(const float*)d_in[12];
  const float* we1=(const float*)d_in[13]; const float* be1=(const float*)d_in[14];
  const float* we2=(const float*)d_in[15]; const float* be2=(const float*)d_in[16];
  const float* wd1=(const float*)d_in[17]; const float* bd1=(const float*)d_in[18];
  const float* wd0=(const float*)d_in[19]; const float* bd0=(const float*)d_in[20];
  const float* wo =(const float*)d_in[21]; const float* bo =(const float*)d_in[22];
  float* out = (float*)d_out;
  char* ws = (char*)d_ws;

  float*    kinv  = (float*)(ws + WS_KINV);
  unsigned* zmax  = (unsigned*)(ws + WS_ZMAX);
  unsigned* zbuf0 = (unsigned*)(ws + WS_ZBUF0);
  unsigned* zbuf1 = (unsigned*)(ws + WS_ZBUF1);
  float*    acc0  = (float*)(ws + WS_ACC0);
  float*    acc1  = (float*)(ws + WS_ACC1);
  bf16* xin = (bf16*)(ws + WS_XIN);
  bf16* h1  = (bf16*)(ws + WS_H1);
  bf16* h2  = (bf16*)(ws + WS_H2);
  bf16* e0  = (bf16*)(ws + WS_E0);
  bf16* e1  = (bf16*)(ws + WS_E1);
  bf16* e2  = (bf16*)(ws + WS_E2);
  bf16* d1  = (bf16*)(ws + WS_D1);
  bf16* d0h = (bf16*)(ws + WS_D0H);
  bf16* wtb = (bf16*)(ws + WS_WT);

  // ---- weight repack ----
  k_wprep<5,8,32,32>    <<<12, 256, 0, stream>>>(fw1, wtb + WT_F1);
  k_wprep<32,32,32,32>  <<<36, 256, 0, stream>>>(fw2, wtb + WT_F2);
  k_wprep<32,32,3,16>   <<<18, 256, 0, stream>>>(fw3, wtb + WT_F3);
  k_wprep<5,8,32,32>    <<<12, 256, 0, stream>>>(we0, wtb + WT_E0);
  k_wprep<32,32,64,64>  <<<72, 256, 0, stream>>>(we1, wtb + WT_E1);
  k_wprep<64,64,128,128><<<288,256, 0, stream>>>(we2, wtb + WT_E2);
  k_wprep<192,192,64,64><<<432,256, 0, stream>>>(wd1, wtb + WT_D1);
  k_wprep<96,96,32,32>  <<<108,256, 0, stream>>>(wd0, wtb + WT_D0);
  k_wprep<32,32,3,16>   <<<18, 256, 0, stream>>>(wo,  wtb + WT_O);

  // ---- splat ----
  hipMemsetAsync(zmax, 0, 32, stream);
  hipMemsetAsync(zbuf0, 0x7f, 6291456, stream);
  hipMemsetAsync(zbuf1, 0x7f, 6291456, stream);
  hipMemsetAsync(acc0, 0, 25165824, stream);
  hipMemsetAsync(acc1, 0, 25165824, stream);
  k_mats<<<1, 64, 0, stream>>>(Ks, kinv);
  dim3 gpix(HW_/256, B_);
  k_proj<<<gpix, 256, 0, stream>>>(Ds, Kt, dT, kinv, zmax, zbuf0, zbuf1, out);
  k_zmerge<<<1536, 256, 0, stream>>>(zbuf0, zbuf1);
  k_acc<<<gpix, 256, 0, stream>>>(Is, Ds, Kt, dT, kinv, (const float*)zbuf0, zmax, acc0, acc1);
  k_norm<<<gpix, 256, 0, stream>>>(acc0, acc1, out);

  // halo totals (blocks of 256)
  const int hXIN = (8*1796*1 + 255)/256;
  const int hC32 = (8*1796*4 + 255)/256;
  const int hE1  = (8*900*8 + 255)/256;
  const int hE2  = (8*452*16 + 255)/256;
  const int hD0H = (4*1796*4 + 255)/256;

  // ---- flow net ----
  k_halo<8><<<hXIN, 256, 0, stream>>>(xin, H_+2, W_+2, 8);
  k_packF<<<gpix, 256, 0, stream>>>(Is, Ds, out, xin);
  k_halo<32><<<hC32, 256, 0, stream>>>(h1, H_+2, W_+2, 8);
  k_gconv<8,0,1,4,2,0,32><<<dim3(2,384,8), 256, 0, stream>>>(
      xin, nullptr, wtb+WT_F1, fb1, h1, nullptr, H_+2, W_+2, 0,0, H_+2, W_+2, 0);
  k_halo<32><<<hC32, 256, 0, stream>>>(h2, H_+2, W_+2, 8);
  k_gconv<32,0,1,4,2,0,32><<<dim3(2,384,8), 256, 0, stream>>>(
      h1, nullptr, wtb+WT_F2, fb2, h2, nullptr, H_+2, W_+2, 0,0, H_+2, W_+2, 0);
  k_gconv<32,0,1,4,1,1,16><<<dim3(2,384,8), 256, 0, stream>>>(
      h2, nullptr, wtb+WT_F3, fb3, nullptr, out, H_+2, W_+2, 0,0, 0,0, 0);

  // ---- unet encoder ----
  k_packU<<<gpix, 256, 0, stream>>>(out, xin);
  k_halo<32><<<hC32, 256, 0, stream>>>(e0, H_+2, W_+2, 8);
  k_gconv<8,0,1,4,2,0,32><<<dim3(2,384,8), 256, 0, stream>>>(
      xin, nullptr, wtb+WT_E0, be0, e0, nullptr, H_+2, W_+2, 0,0, H_+2, W_+2, 0);
  k_halo<64><<<hE1, 256, 0, stream>>>(e1, H2_+2, W2_+2, 8);
  k_gconv<32,0,2,2,4,0,64><<<dim3(2,192,8), 256, 0, stream>>>(
      e0, nullptr, wtb+WT_E1, be1, e1, nullptr, H_+2, W_+2, 0,0, H2_+2, W2_+2, 0);
  k_halo<128><<<hE2, 256, 0, stream>>>(e2, H4_+2, W4_+2, 8);
  k_gconv<64,0,2,2,4,0,128><<<dim3(1,96,16), 256, 0, stream>>>(
      e1, nullptr, wtb+WT_E2, be2, e2, nullptr, H2_+2, W2_+2, 0,0, H4_+2, W4_+2, 0);

  // ---- decoder: d1 full-batch, d0/out3 half-batch ----
  k_halo<64><<<hE1, 256, 0, stream>>>(d1, H2_+2, W2_+2, 8);
  k_gconv<192,128,1,2,4,0,64><<<dim3(2,192,8), 256, 0, stream>>>(
      e1, e2, wtb+WT_D1, bd1, d1, nullptr, H2_+2, W2_+2, H4_+2, W4_+2, H2_+2, W2_+2, 0);

  const size_t e0bStride = (size_t)(H_+2)*(W_+2)*32;
  const size_t d1bStride = (size_t)(H2_+2)*(W2_+2)*64;
  k_halo<32><<<hD0H, 256, 0, stream>>>(d0h, H_+2, W_+2, 4);
  for (int h = 0; h < 2; h++){
    const bf16* e0h = e0 + (size_t)h*4*e0bStride;
    const bf16* d1h = d1 + (size_t)h*4*d1bStride;
    k_gconv<96,64,1,4,2,0,32><<<dim3(2,384,4), 256, 0, stream>>>(
        e0h, d1h, wtb+WT_D0, bd0, d0h, nullptr, H_+2, W_+2, H2_+2, W2_+2, H_+2, W_+2, 0);
    k_gconv<32,0,1,4,1,2,16><<<dim3(2,384,4), 256, 0, stream>>>(
        d0h, nullptr, wtb+WT_O, bo, nullptr, out, H_+2, W_+2, 0,0, 0,0, h*4);
  }
}